// Round 4
// baseline (630.172 us; speedup 1.0000x reference)
//
#include <hip/hip_runtime.h>
#include <hip/hip_bf16.h>
#include <stdint.h>

// x[2,8192,2048] f32, weight[2048,2048] fp8e4m3fn *pushed as f32*, out f32
#define M_DIM 16384
#define N_DIM 2048
#define K_DIM 2048

#define BM 128
#define BN 128
#define BK 64                  // fp8 elements per K-step (2 MFMA k-steps)
#define NTILES (K_DIM / BK)    // 32
#define GRID_M (M_DIM / BM)    // 128
#define GRID_N (N_DIM / BN)    // 16

typedef float    f32x4 __attribute__((ext_vector_type(4)));
typedef uint32_t u32x4 __attribute__((ext_vector_type(4)));

__device__ inline float bf16_bits_to_f32(uint16_t h) {
    union { uint32_t u; float f; } v; v.u = ((uint32_t)h) << 16; return v.f;
}
// scalar scales: 0 / inf / nan / junk are implausible (s=0 was the round-1/2 bug)
__device__ inline bool plaus_scalar(float v) {
    float a = fabsf(v);
    return (a > 1e-5f) && (a < 1e5f);
}
// weight elements: exact 0 is legitimate (small w rounds to fp8 zero)
__device__ inline bool plaus_w(float v) {
    float a = fabsf(v);
    return (v == 0.0f) || ((a > 1e-6f) && (a < 1e4f));
}

__global__ __launch_bounds__(256) void fused_fp8_gemm(
    const float* __restrict__ X,      // [M][K] f32
    const void*  __restrict__ Wp,     // [N][K] — f32 (expected) or raw fp8 bytes
    const void*  __restrict__ wscale_p,
    const void*  __restrict__ iscale_p,
    float* __restrict__ out)
{
    __shared__ uint8_t smA[2][BM * BK];   // 8 KB each
    __shared__ uint8_t smB[2][BN * BK];

    const int tid  = threadIdx.x;
    const int lane = tid & 63;
    const int wid  = tid >> 6;

    // --- scalar reads: f32-first (harness normalizes to f32), bf16-bits fallback
    const float is_f32 = *(const float*)iscale_p;
    const float is_bf  = bf16_bits_to_f32(*(const uint16_t*)iscale_p);
    const bool  is_fb  = !plaus_scalar(is_f32);
    const float s      = is_fb ? is_bf : is_f32;

    const float ws_f32 = *(const float*)wscale_p;
    const float ws_bf  = bf16_bits_to_f32(*(const uint16_t*)wscale_p);
    const bool  ws_fb  = !plaus_scalar(ws_f32);
    const float wsc    = ws_fb ? ws_bf : ws_f32;

    const float rs = 1.0f / s;
    const float sc = wsc * s;

    // --- weight storage vote: f32 storage -> ~64/64 plausible; raw e4m3 bytes
    // read as f32 -> mostly wild exponents (~8/64). Block-uniform, one load/lane.
    const float*   Wf = (const float*)Wp;
    const uint8_t* Wb = (const uint8_t*)Wp;
    const bool w_is_f32 = (__popcll(__ballot(plaus_w(Wf[lane]))) >= 48);

    // canary: 1.0e-3 * (1 + .1*is_fb + .2*ws_fb + .4*byte-path)
    const float canary = 1.0e-3f * (1.0f + (is_fb ? 0.1f : 0.0f)
                                         + (ws_fb ? 0.2f : 0.0f)
                                         + (w_is_f32 ? 0.0f : 0.4f));

    // Bijective XCD swizzle (2048 % 8 == 0); consecutive wg share bm -> L2 reuse.
    const int bid = blockIdx.x;
    const int wg  = (bid & 7) * (GRID_M * GRID_N / 8) + (bid >> 3);
    const int bm  = wg >> 4;
    const int bn  = wg & 15;
    const int rowBase = bm * BM;
    const int colBase = bn * BN;

    const int wrow = (wid >> 1) * 64;
    const int wcol = (wid & 1) * 64;

    // Staging: thread t owns row (t>>1), 32-element half (t&1) of the 128x64 tile.
    const int ar = tid >> 1;
    const int ah = (tid & 1) * 32;

    const float*   Xrow  = X  + (size_t)(rowBase + ar) * K_DIM;
    const float*   WfRow = Wf + (size_t)(colBase + ar) * K_DIM;
    const uint8_t* WbRow = Wb + (size_t)(colBase + ar) * K_DIM;

    float4 areg[8];    // 32 f32 of x
    float4 bregf[8];   // 32 f32 of W (f32 path)
    u32x4  bregb[2];   // 32 raw bytes (fallback path)

    auto load_tile = [&](int kt) {
        const int k0 = kt * BK;
#pragma unroll
        for (int j = 0; j < 8; ++j)
            areg[j] = *(const float4*)(Xrow + k0 + ah + j * 4);
        if (w_is_f32) {
#pragma unroll
            for (int j = 0; j < 8; ++j)
                bregf[j] = *(const float4*)(WfRow + k0 + ah + j * 4);
        } else {
#pragma unroll
            for (int j = 0; j < 2; ++j)
                bregb[j] = *(const u32x4*)(WbRow + k0 + ah + j * 16);
        }
    };

    auto write_tile = [&](int buf) {
        uint32_t aq[8];
#pragma unroll
        for (int j = 0; j < 8; ++j) {
            float q0 = fminf(fmaxf(areg[j].x * rs, -448.f), 448.f);
            float q1 = fminf(fmaxf(areg[j].y * rs, -448.f), 448.f);
            float q2 = fminf(fmaxf(areg[j].z * rs, -448.f), 448.f);
            float q3 = fminf(fmaxf(areg[j].w * rs, -448.f), 448.f);
            int p = __builtin_amdgcn_cvt_pk_fp8_f32(q0, q1, 0, false); // bytes 0,1
            p     = __builtin_amdgcn_cvt_pk_fp8_f32(q2, q3, p, true);  // bytes 2,3
            aq[j] = (uint32_t)p;
        }
        *(u32x4*)&smA[buf][ar * BK + ah]      = *(const u32x4*)&aq[0];
        *(u32x4*)&smA[buf][ar * BK + ah + 16] = *(const u32x4*)&aq[4];

        if (w_is_f32) {
            uint32_t bq[8];
#pragma unroll
            for (int j = 0; j < 8; ++j) {
                // values are e4m3-representable -> conversion exact, no clamp needed
                int p = __builtin_amdgcn_cvt_pk_fp8_f32(bregf[j].x, bregf[j].y, 0, false);
                p     = __builtin_amdgcn_cvt_pk_fp8_f32(bregf[j].z, bregf[j].w, p, true);
                bq[j] = (uint32_t)p;
            }
            *(u32x4*)&smB[buf][ar * BK + ah]      = *(const u32x4*)&bq[0];
            *(u32x4*)&smB[buf][ar * BK + ah + 16] = *(const u32x4*)&bq[4];
        } else {
            *(u32x4*)&smB[buf][ar * BK + ah]      = bregb[0];
            *(u32x4*)&smB[buf][ar * BK + ah + 16] = bregb[1];
        }
    };

    f32x4 acc[4][4] = {};

    load_tile(0);
    write_tile(0);
    __syncthreads();

    for (int kt = 0; kt < NTILES; ++kt) {
        const int cur = kt & 1;
        if (kt + 1 < NTILES) load_tile(kt + 1);

        const uint8_t* pA = smA[cur];
        const uint8_t* pB = smB[cur];
        const int afr  = lane & 15;           // fragment row (A) / out-col row (B)
        const int koff = (lane >> 4) << 3;    // k byte offset within 32B k-step
#pragma unroll
        for (int kk = 0; kk < 2; ++kk) {
            long long a[4], b[4];
#pragma unroll
            for (int m = 0; m < 4; ++m)
                a[m] = *(const long long*)(pA + (wrow + m * 16 + afr) * BK + kk * 32 + koff);
#pragma unroll
            for (int n = 0; n < 4; ++n)
                b[n] = *(const long long*)(pB + (wcol + n * 16 + afr) * BK + kk * 32 + koff);
#pragma unroll
            for (int m = 0; m < 4; ++m)
#pragma unroll
                for (int n = 0; n < 4; ++n)
                    acc[m][n] = __builtin_amdgcn_mfma_f32_16x16x32_fp8_fp8(
                        a[m], b[n], acc[m][n], 0, 0, 0);
        }

        if (kt + 1 < NTILES) write_tile(cur ^ 1);
        __syncthreads();
    }

    // C/D layout: col = lane&15, row = (lane>>4)*4 + reg.
    const int crow = (lane >> 4) << 2;
    const int ccol = lane & 15;
#pragma unroll
    for (int m = 0; m < 4; ++m) {
#pragma unroll
        for (int n = 0; n < 4; ++n) {
            const size_t base = (size_t)(rowBase + wrow + m * 16 + crow) * N_DIM
                              + (colBase + wcol + n * 16 + ccol);
#pragma unroll
            for (int r = 0; r < 4; ++r)
                out[base + (size_t)r * N_DIM] = acc[m][n][r] * sc + canary;
        }
    }
}

extern "C" void kernel_launch(void* const* d_in, const int* in_sizes, int n_in,
                              void* d_out, int out_size, void* d_ws, size_t ws_size,
                              hipStream_t stream) {
    const float* x      = (const float*)d_in[0];
    const void*  w      = d_in[1];
    const void*  wscale = d_in[2];
    const void*  iscale = d_in[3];
    float*       out    = (float*)d_out;

    fused_fp8_gemm<<<GRID_M * GRID_N, 256, 0, stream>>>(x, w, wscale, iscale, out);
}

// Round 5
// 281.292 us; speedup vs baseline: 2.2403x; 2.2403x over previous
//
#include <hip/hip_runtime.h>
#include <hip/hip_bf16.h>
#include <stdint.h>

// x[2,8192,2048] f32; weight[2048,2048] fp8e4m3fn pushed as f32 values;
// scales pushed as f32 scalars (established rounds 0-4). out[2,8192,2048] f32.
#define M_DIM 16384
#define N_DIM 2048
#define K_DIM 2048

#define BM 128
#define BN 128
#define BK 64                  // fp8 bytes per K-tile (2 MFMA k-steps)
#define NTILES (K_DIM / BK)    // 32
#define GRID_M (M_DIM / BM)    // 128
#define GRID_N (N_DIM / BN)    // 16

typedef float    f32x4 __attribute__((ext_vector_type(4)));
typedef uint32_t u32x4 __attribute__((ext_vector_type(4)));

__device__ inline uint32_t quant4(float4 v, float rs) {
    float q0 = fminf(fmaxf(v.x * rs, -448.f), 448.f);
    float q1 = fminf(fmaxf(v.y * rs, -448.f), 448.f);
    float q2 = fminf(fmaxf(v.z * rs, -448.f), 448.f);
    float q3 = fminf(fmaxf(v.w * rs, -448.f), 448.f);
    int p = __builtin_amdgcn_cvt_pk_fp8_f32(q0, q1, 0, false);  // bytes 0,1
    p     = __builtin_amdgcn_cvt_pk_fp8_f32(q2, q3, p, true);   // bytes 2,3
    return (uint32_t)p;
}

// ---------------------------------------------------------------------------
// Pass 1: quantize X (f32 -> fp8 e4m3, RNE). 8.4M u32 out; 2048 blk x 256 thr x 16.
// ---------------------------------------------------------------------------
__global__ __launch_bounds__(256) void quant_x_kernel(
    const float* __restrict__ x, const float* __restrict__ s_ptr,
    uint32_t* __restrict__ xq)
{
    const float rs = 1.0f / s_ptr[0];   // same math as validated round-4 kernel
    const float4* xf4 = (const float4*)x;
    const int base = blockIdx.x * 4096 + threadIdx.x;
#pragma unroll
    for (int k = 0; k < 16; ++k) {
        const int i = base + k * 256;
        xq[i] = quant4(xf4[i], rs);
    }
}

// ---------------------------------------------------------------------------
// Pass 2: convert W (f32 holding e4m3-representable values -> fp8 bytes, exact).
// 1M u32 out; 1024 blk x 256 thr x 4.
// ---------------------------------------------------------------------------
__global__ __launch_bounds__(256) void conv_w_kernel(
    const float* __restrict__ w, uint32_t* __restrict__ wq)
{
    const float4* wf4 = (const float4*)w;
    const int base = blockIdx.x * 1024 + threadIdx.x;
#pragma unroll
    for (int k = 0; k < 4; ++k) {
        const int i = base + k * 256;
        wq[i] = quant4(wf4[i], 1.0f);   // clamp is a no-op for e4m3 values
    }
}

// ---------------------------------------------------------------------------
// Pass 3: fp8 GEMM, m97/m145 structure: global_load_lds width=16 (linear LDS,
// conflict-free staging), double-buffered 2-barrier loop, 16x16x32 fp8 MFMA.
// ---------------------------------------------------------------------------
__global__ __launch_bounds__(256) void gemm_fp8_kernel(
    const uint8_t* __restrict__ Aq,   // [M][K] fp8
    const uint8_t* __restrict__ Wq,   // [N][K] fp8
    const float* __restrict__ wscale,
    const float* __restrict__ iscale,
    float* __restrict__ out)
{
    __shared__ uint8_t smA[2][BM * BK];  // 8 KB each
    __shared__ uint8_t smB[2][BN * BK];

    const int tid  = threadIdx.x;
    const int lane = tid & 63;
    const int wid  = tid >> 6;

    // Bijective XCD swizzle (2048 % 8 == 0); 16 consecutive wg share bm -> the
    // 256 KB Aq panel and whole Wq (4 MB) are L2-resident per XCD.
    const int bid = blockIdx.x;
    const int wg  = (bid & 7) * (GRID_M * GRID_N / 8) + (bid >> 3);
    const int bm  = wg >> 4;
    const int bn  = wg & 15;
    const int rowBase = bm * BM;
    const int colBase = bn * BN;

    // Wave's 64x64 output quadrant
    const int wrow = (wid >> 1) * 64;
    const int wcol = (wid & 1) * 64;

    // Staging: tile = 8 chunks x 1024 B; wave w stages chunks {w, w+4} of A and B.
    // gload_lds lands lane l at base + l*16 => LDS linear [row][64B] given
    // global addr row = chunk*16 + l/4, bytecol = (l%4)*16.
    const int sr = lane >> 2;           // 0..15
    const int sc4 = (lane & 3) * 16;    // 0,16,32,48
    auto stage = [&](int buf, int kt) {
        const int k0 = kt * BK;
#pragma unroll
        for (int j = 0; j < 2; ++j) {
            const int chunk = j * 4 + wid;                  // 0..7
            const int row   = chunk * 16 + sr;
            const uint8_t* gA = Aq + (size_t)(rowBase + row) * K_DIM + k0 + sc4;
            __builtin_amdgcn_global_load_lds(
                (const __attribute__((address_space(1))) void*)gA,
                (__attribute__((address_space(3))) void*)&smA[buf][chunk * 1024],
                16, 0, 0);
            const uint8_t* gB = Wq + (size_t)(colBase + row) * K_DIM + k0 + sc4;
            __builtin_amdgcn_global_load_lds(
                (const __attribute__((address_space(1))) void*)gB,
                (__attribute__((address_space(3))) void*)&smB[buf][chunk * 1024],
                16, 0, 0);
        }
    };

    f32x4 acc[4][4] = {};

    stage(0, 0);
    __syncthreads();   // compiler drains vmcnt(0) before s_barrier

    for (int kt = 0; kt < NTILES; ++kt) {
        const int cur = kt & 1;
        if (kt + 1 < NTILES) stage(cur ^ 1, kt + 1);   // DMA prefetch under compute

        const uint8_t* pA = smA[cur];
        const uint8_t* pB = smB[cur];
        const int afr  = lane & 15;          // fragment row (A rows / B out-cols)
        const int koff = (lane >> 4) << 3;   // k byte offset 0,8,16,24
#pragma unroll
        for (int kk = 0; kk < 2; ++kk) {
            long long a[4], b[4];
#pragma unroll
            for (int m = 0; m < 4; ++m)
                a[m] = *(const long long*)(pA + (wrow + m * 16 + afr) * BK + kk * 32 + koff);
#pragma unroll
            for (int n = 0; n < 4; ++n)
                b[n] = *(const long long*)(pB + (wcol + n * 16 + afr) * BK + kk * 32 + koff);
#pragma unroll
            for (int m = 0; m < 4; ++m)
#pragma unroll
                for (int n = 0; n < 4; ++n)
                    acc[m][n] = __builtin_amdgcn_mfma_f32_16x16x32_fp8_fp8(
                        a[m], b[n], acc[m][n], 0, 0, 0);
        }
        __syncthreads();   // joins waves + drains prefetch before buffer swap
    }

    // C/D layout: col = lane&15, row = (lane>>4)*4 + reg (validated round 4).
    const float sc = wscale[0] * iscale[0];
    const int crow = (lane >> 4) << 2;
    const int ccol = lane & 15;
#pragma unroll
    for (int m = 0; m < 4; ++m) {
#pragma unroll
        for (int n = 0; n < 4; ++n) {
            const size_t base = (size_t)(rowBase + wrow + m * 16 + crow) * N_DIM
                              + (colBase + wcol + n * 16 + ccol);
#pragma unroll
            for (int r = 0; r < 4; ++r)
                out[base + (size_t)r * N_DIM] = acc[m][n][r] * sc;
        }
    }
}

// ---------------------------------------------------------------------------
// Fallback (ws too small): round-4 fused kernel with direct f32 reads — proven.
// ---------------------------------------------------------------------------
__global__ __launch_bounds__(256) void fused_fp8_gemm(
    const float* __restrict__ X, const float* __restrict__ Wf,
    const float* __restrict__ wscale, const float* __restrict__ iscale,
    float* __restrict__ out)
{
    __shared__ uint8_t smA[2][BM * BK];
    __shared__ uint8_t smB[2][BN * BK];

    const int tid  = threadIdx.x;
    const int lane = tid & 63;
    const int wid  = tid >> 6;

    const float s  = iscale[0];
    const float rs = 1.0f / s;
    const float sc = wscale[0] * s;

    const int bid = blockIdx.x;
    const int wg  = (bid & 7) * (GRID_M * GRID_N / 8) + (bid >> 3);
    const int bm  = wg >> 4;
    const int bn  = wg & 15;
    const int rowBase = bm * BM;
    const int colBase = bn * BN;
    const int wrow = (wid >> 1) * 64;
    const int wcol = (wid & 1) * 64;
    const int ar = tid >> 1;
    const int ah = (tid & 1) * 32;

    const float* Xrow = X  + (size_t)(rowBase + ar) * K_DIM;
    const float* Wrow = Wf + (size_t)(colBase + ar) * K_DIM;

    float4 areg[8], breg[8];
    auto load_tile = [&](int kt) {
        const int k0 = kt * BK;
#pragma unroll
        for (int j = 0; j < 8; ++j) areg[j] = *(const float4*)(Xrow + k0 + ah + j * 4);
#pragma unroll
        for (int j = 0; j < 8; ++j) breg[j] = *(const float4*)(Wrow + k0 + ah + j * 4);
    };
    auto write_tile = [&](int buf) {
        uint32_t aq[8], bq[8];
#pragma unroll
        for (int j = 0; j < 8; ++j) { aq[j] = quant4(areg[j], rs); bq[j] = quant4(breg[j], 1.0f); }
        *(u32x4*)&smA[buf][ar * BK + ah]      = *(const u32x4*)&aq[0];
        *(u32x4*)&smA[buf][ar * BK + ah + 16] = *(const u32x4*)&aq[4];
        *(u32x4*)&smB[buf][ar * BK + ah]      = *(const u32x4*)&bq[0];
        *(u32x4*)&smB[buf][ar * BK + ah + 16] = *(const u32x4*)&bq[4];
    };

    f32x4 acc[4][4] = {};
    load_tile(0); write_tile(0); __syncthreads();
    for (int kt = 0; kt < NTILES; ++kt) {
        const int cur = kt & 1;
        if (kt + 1 < NTILES) load_tile(kt + 1);
        const uint8_t* pA = smA[cur];
        const uint8_t* pB = smB[cur];
        const int afr = lane & 15, koff = (lane >> 4) << 3;
#pragma unroll
        for (int kk = 0; kk < 2; ++kk) {
            long long a[4], b[4];
#pragma unroll
            for (int m = 0; m < 4; ++m)
                a[m] = *(const long long*)(pA + (wrow + m * 16 + afr) * BK + kk * 32 + koff);
#pragma unroll
            for (int n = 0; n < 4; ++n)
                b[n] = *(const long long*)(pB + (wcol + n * 16 + afr) * BK + kk * 32 + koff);
#pragma unroll
            for (int m = 0; m < 4; ++m)
#pragma unroll
                for (int n = 0; n < 4; ++n)
                    acc[m][n] = __builtin_amdgcn_mfma_f32_16x16x32_fp8_fp8(
                        a[m], b[n], acc[m][n], 0, 0, 0);
        }
        if (kt + 1 < NTILES) write_tile(cur ^ 1);
        __syncthreads();
    }
    const int crow = (lane >> 4) << 2, ccol = lane & 15;
#pragma unroll
    for (int m = 0; m < 4; ++m)
#pragma unroll
        for (int n = 0; n < 4; ++n) {
            const size_t base = (size_t)(rowBase + wrow + m * 16 + crow) * N_DIM
                              + (colBase + wcol + n * 16 + ccol);
#pragma unroll
            for (int r = 0; r < 4; ++r)
                out[base + (size_t)r * N_DIM] = acc[m][n][r] * sc;
        }
}

extern "C" void kernel_launch(void* const* d_in, const int* in_sizes, int n_in,
                              void* d_out, int out_size, void* d_ws, size_t ws_size,
                              hipStream_t stream) {
    const float* x      = (const float*)d_in[0];
    const float* w      = (const float*)d_in[1];   // fp8 values stored as f32
    const float* wscale = (const float*)d_in[2];
    const float* iscale = (const float*)d_in[3];
    float*       out    = (float*)d_out;

    const size_t needA = (size_t)M_DIM * K_DIM;    // 33.5 MB fp8 X
    const size_t needW = (size_t)N_DIM * K_DIM;    //  4.2 MB fp8 W
    if (ws_size >= needA + needW) {
        uint32_t* xq = (uint32_t*)d_ws;
        uint32_t* wq = (uint32_t*)((uint8_t*)d_ws + needA);
        quant_x_kernel<<<2048, 256, 0, stream>>>(x, iscale, xq);
        conv_w_kernel<<<1024, 256, 0, stream>>>(w, wq);
        gemm_fp8_kernel<<<GRID_M * GRID_N, 256, 0, stream>>>(
            (const uint8_t*)xq, (const uint8_t*)wq, wscale, iscale, out);
    } else {
        fused_fp8_gemm<<<GRID_M * GRID_N, 256, 0, stream>>>(x, w, wscale, iscale, out);
    }
}

// Round 6
// 134.767 us; speedup vs baseline: 4.6760x; 2.0872x over previous
//
#include <hip/hip_runtime.h>
#include <hip/hip_bf16.h>
#include <stdint.h>

// x[2,8192,2048] f32; weight[2048,2048] fp8e4m3fn pushed as f32 values;
// scales pushed as f32 scalars (established rounds 0-5). out[2,8192,2048] f32.
#define M_DIM 16384
#define N_DIM 2048
#define K_DIM 2048

#define BM 128
#define BN 128
#define BK 64                  // fp8 bytes per K-tile (2 MFMA k-steps)
#define NTILES (K_DIM / BK)    // 32
#define GRID_M (M_DIM / BM)    // 128
#define GRID_N (N_DIM / BN)    // 16

typedef float     f32x4 __attribute__((ext_vector_type(4)));
typedef uint32_t  u32x4 __attribute__((ext_vector_type(4)));
typedef long long i64x2 __attribute__((ext_vector_type(2)));

__device__ inline uint32_t quant4(float4 v, float rs) {
    float q0 = fminf(fmaxf(v.x * rs, -448.f), 448.f);
    float q1 = fminf(fmaxf(v.y * rs, -448.f), 448.f);
    float q2 = fminf(fmaxf(v.z * rs, -448.f), 448.f);
    float q3 = fminf(fmaxf(v.w * rs, -448.f), 448.f);
    int p = __builtin_amdgcn_cvt_pk_fp8_f32(q0, q1, 0, false);  // bytes 0,1
    p     = __builtin_amdgcn_cvt_pk_fp8_f32(q2, q3, p, true);   // bytes 2,3
    return (uint32_t)p;
}

// Permuted fp8 layout (fragment-contiguous): within each row's 64B k-tile,
//   pcol = kgrp*16 + kk*8 + b   <->   ocol = kk*32 + kgrp*8 + b
// so one ds_read_b128 at slot kgrp yields both kk fragments for a lane.

// ---------------------------------------------------------------------------
// Pass 1: quantize X f32 -> permuted fp8. One 16B chunk (t,kgrp) per iter.
// ---------------------------------------------------------------------------
__global__ __launch_bounds__(256) void quant_x_perm(
    const float* __restrict__ x, const float* __restrict__ s_ptr,
    u32x4* __restrict__ xq)
{
    const float rs = 1.0f / s_ptr[0];
    const int g0 = blockIdx.x * 1024 + threadIdx.x;
#pragma unroll
    for (int k = 0; k < 4; ++k) {
        const int g    = g0 + k * 256;
        const int row  = g >> 7;         // 128 16B-chunks per 2048-col row
        const int c16  = g & 127;
        const int t    = c16 >> 2;
        const int kgrp = c16 & 3;
        const float* src = x + (size_t)row * K_DIM + t * 64 + kgrp * 8;
        float4 v0 = *(const float4*)(src);        // kk=0, b0..3
        float4 v1 = *(const float4*)(src + 4);    // kk=0, b4..7
        float4 v2 = *(const float4*)(src + 32);   // kk=1, b0..3
        float4 v3 = *(const float4*)(src + 36);   // kk=1, b4..7
        u32x4 o;
        o.x = quant4(v0, rs); o.y = quant4(v1, rs);
        o.z = quant4(v2, rs); o.w = quant4(v3, rs);
        xq[g] = o;
    }
}

// ---------------------------------------------------------------------------
// Pass 2: W f32 (e4m3-representable) -> permuted fp8 bytes (exact).
// ---------------------------------------------------------------------------
__global__ __launch_bounds__(256) void conv_w_perm(
    const float* __restrict__ w, u32x4* __restrict__ wq)
{
    const int g    = blockIdx.x * 256 + threadIdx.x;
    const int row  = g >> 7;
    const int c16  = g & 127;
    const int t    = c16 >> 2;
    const int kgrp = c16 & 3;
    const float* src = w + (size_t)row * K_DIM + t * 64 + kgrp * 8;
    float4 v0 = *(const float4*)(src);
    float4 v1 = *(const float4*)(src + 4);
    float4 v2 = *(const float4*)(src + 32);
    float4 v3 = *(const float4*)(src + 36);
    u32x4 o;
    o.x = quant4(v0, 1.0f); o.y = quant4(v1, 1.0f);
    o.z = quant4(v2, 1.0f); o.w = quant4(v3, 1.0f);
    wq[g] = o;
}

// ---------------------------------------------------------------------------
// Pass 3: fp8 GEMM. global_load_lds width=16, LDS linear-written; XOR swizzle
// realized by pre-swizzling the GLOBAL source position (rule #21) so the
// ds_read_b128 fragment reads are bank-uniform (8 dwords/bank, conflict-free).
// LDS slot for (row, kgrp): slot = kgrp ^ ((row>>1)&3).
// ---------------------------------------------------------------------------
__global__ __launch_bounds__(256) void gemm_fp8_kernel(
    const uint8_t* __restrict__ Aq,   // [M][K] permuted fp8
    const uint8_t* __restrict__ Wq,   // [N][K] permuted fp8
    const float* __restrict__ wscale,
    const float* __restrict__ iscale,
    float* __restrict__ out)
{
    __shared__ uint8_t smA[2][BM * BK];  // 8 KB each
    __shared__ uint8_t smB[2][BN * BK];

    const int tid  = threadIdx.x;
    const int lane = tid & 63;
    const int wid  = tid >> 6;

    // Bijective XCD swizzle (2048 % 8 == 0); consecutive wg share bm.
    const int bid = blockIdx.x;
    const int wg  = (bid & 7) * (GRID_M * GRID_N / 8) + (bid >> 3);
    const int bm  = wg >> 4;
    const int bn  = wg & 15;
    const int rowBase = bm * BM;
    const int colBase = bn * BN;

    const int wrow = (wid >> 1) * 64;
    const int wcol = (wid & 1) * 64;

    // Staging: lane l of chunk c covers LDS row c*16 + l/4, pos16 l%4.
    // Needed global 16B position: (l%4) ^ ((row>>1)&3) = (l&3) ^ ((l>>3)&3).
    const int sr    = lane >> 2;                              // 0..15
    const int spos  = ((lane & 3) ^ ((lane >> 3) & 3)) * 16;  // pre-swizzled src
    auto stage = [&](int buf, int kt) {
        const int k0 = kt * BK;
#pragma unroll
        for (int j = 0; j < 2; ++j) {
            const int chunk = j * 4 + wid;              // 0..7
            const int row   = chunk * 16 + sr;
            const uint8_t* gA = Aq + (size_t)(rowBase + row) * K_DIM + k0 + spos;
            __builtin_amdgcn_global_load_lds(
                (const __attribute__((address_space(1))) void*)gA,
                (__attribute__((address_space(3))) void*)&smA[buf][chunk * 1024],
                16, 0, 0);
            const uint8_t* gB = Wq + (size_t)(colBase + row) * K_DIM + k0 + spos;
            __builtin_amdgcn_global_load_lds(
                (const __attribute__((address_space(1))) void*)gB,
                (__attribute__((address_space(3))) void*)&smB[buf][chunk * 1024],
                16, 0, 0);
        }
    };

    // Fragment read offsets: one b128 per (operand, m) = both kk fragments.
    const int afr  = lane & 15;
    const int kgrp = lane >> 4;
    const int soff = (kgrp ^ ((afr >> 1) & 3)) * 16;   // (row>>1)&3 == (afr>>1)&3
    const int aOff = (wrow + afr) * 64 + soff;
    const int bOff = (wcol + afr) * 64 + soff;

    f32x4 acc[4][4] = {};

    stage(0, 0);
    __syncthreads();

    for (int kt = 0; kt < NTILES; ++kt) {
        const int cur = kt & 1;
        if (kt + 1 < NTILES) stage(cur ^ 1, kt + 1);   // DMA prefetch under compute

        const uint8_t* pA = smA[cur];
        const uint8_t* pB = smB[cur];
        i64x2 a[4], b[4];
#pragma unroll
        for (int m = 0; m < 4; ++m)
            a[m] = *(const i64x2*)(pA + aOff + m * 1024);
#pragma unroll
        for (int n = 0; n < 4; ++n)
            b[n] = *(const i64x2*)(pB + bOff + n * 1024);
#pragma unroll
        for (int m = 0; m < 4; ++m)
#pragma unroll
            for (int n = 0; n < 4; ++n) {
                acc[m][n] = __builtin_amdgcn_mfma_f32_16x16x32_fp8_fp8(
                    a[m].x, b[n].x, acc[m][n], 0, 0, 0);
                acc[m][n] = __builtin_amdgcn_mfma_f32_16x16x32_fp8_fp8(
                    a[m].y, b[n].y, acc[m][n], 0, 0, 0);
            }
        __syncthreads();
    }

    // C/D layout: col = lane&15, row = (lane>>4)*4 + reg (validated rounds 4-5).
    const float sc = wscale[0] * iscale[0];
    const int crow = (lane >> 4) << 2;
    const int ccol = lane & 15;
#pragma unroll
    for (int m = 0; m < 4; ++m) {
#pragma unroll
        for (int n = 0; n < 4; ++n) {
            const size_t base = (size_t)(rowBase + wrow + m * 16 + crow) * N_DIM
                              + (colBase + wcol + n * 16 + ccol);
#pragma unroll
            for (int r = 0; r < 4; ++r)
                out[base + (size_t)r * N_DIM] = acc[m][n][r] * sc;
        }
    }
}

// ---------------------------------------------------------------------------
// Fallback (ws too small): proven round-4 fused kernel, unchanged.
// ---------------------------------------------------------------------------
__global__ __launch_bounds__(256) void fused_fp8_gemm(
    const float* __restrict__ X, const float* __restrict__ Wf,
    const float* __restrict__ wscale, const float* __restrict__ iscale,
    float* __restrict__ out)
{
    __shared__ uint8_t smA[2][BM * BK];
    __shared__ uint8_t smB[2][BN * BK];

    const int tid  = threadIdx.x;
    const int lane = tid & 63;
    const int wid  = tid >> 6;

    const float s  = iscale[0];
    const float rs = 1.0f / s;
    const float sc = wscale[0] * s;

    const int bid = blockIdx.x;
    const int wg  = (bid & 7) * (GRID_M * GRID_N / 8) + (bid >> 3);
    const int bm  = wg >> 4;
    const int bn  = wg & 15;
    const int rowBase = bm * BM;
    const int colBase = bn * BN;
    const int wrow = (wid >> 1) * 64;
    const int wcol = (wid & 1) * 64;
    const int ar = tid >> 1;
    const int ah = (tid & 1) * 32;

    const float* Xrow = X  + (size_t)(rowBase + ar) * K_DIM;
    const float* Wrow = Wf + (size_t)(colBase + ar) * K_DIM;

    float4 areg[8], breg[8];
    auto load_tile = [&](int kt) {
        const int k0 = kt * BK;
#pragma unroll
        for (int j = 0; j < 8; ++j) areg[j] = *(const float4*)(Xrow + k0 + ah + j * 4);
#pragma unroll
        for (int j = 0; j < 8; ++j) breg[j] = *(const float4*)(Wrow + k0 + ah + j * 4);
    };
    auto write_tile = [&](int buf) {
        uint32_t aq[8], bq[8];
#pragma unroll
        for (int j = 0; j < 8; ++j) { aq[j] = quant4(areg[j], rs); bq[j] = quant4(breg[j], 1.0f); }
        *(u32x4*)&smA[buf][ar * BK + ah]      = *(const u32x4*)&aq[0];
        *(u32x4*)&smA[buf][ar * BK + ah + 16] = *(const u32x4*)&aq[4];
        *(u32x4*)&smB[buf][ar * BK + ah]      = *(const u32x4*)&bq[0];
        *(u32x4*)&smB[buf][ar * BK + ah + 16] = *(const u32x4*)&bq[4];
    };

    f32x4 acc[4][4] = {};
    load_tile(0); write_tile(0); __syncthreads();
    for (int kt = 0; kt < NTILES; ++kt) {
        const int cur = kt & 1;
        if (kt + 1 < NTILES) load_tile(kt + 1);
        const uint8_t* pA = smA[cur];
        const uint8_t* pB = smB[cur];
        const int afr = lane & 15, koff = (lane >> 4) << 3;
#pragma unroll
        for (int kk = 0; kk < 2; ++kk) {
            long long a[4], b[4];
#pragma unroll
            for (int m = 0; m < 4; ++m)
                a[m] = *(const long long*)(pA + (wrow + m * 16 + afr) * BK + kk * 32 + koff);
#pragma unroll
            for (int n = 0; n < 4; ++n)
                b[n] = *(const long long*)(pB + (wcol + n * 16 + afr) * BK + kk * 32 + koff);
#pragma unroll
            for (int m = 0; m < 4; ++m)
#pragma unroll
                for (int n = 0; n < 4; ++n)
                    acc[m][n] = __builtin_amdgcn_mfma_f32_16x16x32_fp8_fp8(
                        a[m], b[n], acc[m][n], 0, 0, 0);
        }
        if (kt + 1 < NTILES) write_tile(cur ^ 1);
        __syncthreads();
    }
    const int crow = (lane >> 4) << 2, ccol = lane & 15;
#pragma unroll
    for (int m = 0; m < 4; ++m)
#pragma unroll
        for (int n = 0; n < 4; ++n) {
            const size_t base = (size_t)(rowBase + wrow + m * 16 + crow) * N_DIM
                              + (colBase + wcol + n * 16 + ccol);
#pragma unroll
            for (int r = 0; r < 4; ++r)
                out[base + (size_t)r * N_DIM] = acc[m][n][r] * sc;
        }
}

extern "C" void kernel_launch(void* const* d_in, const int* in_sizes, int n_in,
                              void* d_out, int out_size, void* d_ws, size_t ws_size,
                              hipStream_t stream) {
    const float* x      = (const float*)d_in[0];
    const float* w      = (const float*)d_in[1];   // fp8 values stored as f32
    const float* wscale = (const float*)d_in[2];
    const float* iscale = (const float*)d_in[3];
    float*       out    = (float*)d_out;

    const size_t needA = (size_t)M_DIM * K_DIM;    // 33.5 MB fp8 X (permuted)
    const size_t needW = (size_t)N_DIM * K_DIM;    //  4.2 MB fp8 W (permuted)
    if (ws_size >= needA + needW) {
        u32x4* xq = (u32x4*)d_ws;
        u32x4* wq = (u32x4*)((uint8_t*)d_ws + needA);
        quant_x_perm<<<2048, 256, 0, stream>>>(x, iscale, xq);
        conv_w_perm<<<1024, 256, 0, stream>>>(w, wq);
        gemm_fp8_kernel<<<GRID_M * GRID_N, 256, 0, stream>>>(
            (const uint8_t*)d_ws, (const uint8_t*)d_ws + needA, wscale, iscale, out);
    } else {
        fused_fp8_gemm<<<GRID_M * GRID_N, 256, 0, stream>>>(x, w, wscale, iscale, out);
    }
}

// Round 7
// 119.307 us; speedup vs baseline: 5.2819x; 1.1296x over previous
//
#include <hip/hip_runtime.h>
#include <hip/hip_bf16.h>
#include <stdint.h>

// x[2,8192,2048] f32; weight[2048,2048] fp8e4m3fn pushed as f32 values;
// scales pushed as f32 scalars (established rounds 0-6). out[2,8192,2048] f32.
#define M_DIM 16384
#define N_DIM 2048
#define K_DIM 2048

#define BM 128
#define BN 128
#define BK 128                 // fp8 bytes per K-tile (one MX MFMA k-step)
#define NTILES (K_DIM / BK)    // 16
#define GRID_M (M_DIM / BM)    // 128
#define GRID_N (N_DIM / BN)    // 16

typedef float    f32x4 __attribute__((ext_vector_type(4)));
typedef uint32_t u32x4 __attribute__((ext_vector_type(4)));
typedef int      i32x8 __attribute__((ext_vector_type(8)));

#define SCALE_ONE 0x7F7F7F7F   // e8m0 exponent 127 -> 2^0 = 1.0, all byte lanes

__device__ inline uint32_t quant4(float4 v, float rs) {
    float q0 = fminf(fmaxf(v.x * rs, -448.f), 448.f);
    float q1 = fminf(fmaxf(v.y * rs, -448.f), 448.f);
    float q2 = fminf(fmaxf(v.z * rs, -448.f), 448.f);
    float q3 = fminf(fmaxf(v.w * rs, -448.f), 448.f);
    int p = __builtin_amdgcn_cvt_pk_fp8_f32(q0, q1, 0, false);  // bytes 0,1
    p     = __builtin_amdgcn_cvt_pk_fp8_f32(q2, q3, p, true);   // bytes 2,3
    return (uint32_t)p;
}

// ---------------------------------------------------------------------------
// Pass 1: quantize X f32 -> fp8 e4m3 (RNE), plain row-major (MX fragment order
// IS row-major: each lane block = 32 contiguous k bytes).
// ---------------------------------------------------------------------------
__global__ __launch_bounds__(256) void quant_x_kernel(
    const float* __restrict__ x, const float* __restrict__ s_ptr,
    uint32_t* __restrict__ xq)
{
    const float rs = 1.0f / s_ptr[0];
    const float4* xf4 = (const float4*)x;
    const int base = blockIdx.x * 4096 + threadIdx.x;
#pragma unroll
    for (int k = 0; k < 16; ++k) {
        const int i = base + k * 256;
        xq[i] = quant4(xf4[i], rs);
    }
}

// ---------------------------------------------------------------------------
// Pass 2: W f32 (e4m3-representable values) -> fp8 bytes (exact), row-major.
// ---------------------------------------------------------------------------
__global__ __launch_bounds__(256) void conv_w_kernel(
    const float* __restrict__ w, uint32_t* __restrict__ wq)
{
    const float4* wf4 = (const float4*)w;
    const int base = blockIdx.x * 1024 + threadIdx.x;
#pragma unroll
    for (int k = 0; k < 4; ++k) {
        const int i = base + k * 256;
        wq[i] = quant4(wf4[i], 1.0f);
    }
}

// ---------------------------------------------------------------------------
// Pass 3: MX-fp8 GEMM (m148 recipe): mfma_scale_f32_16x16x128_f8f6f4 with
// scales = 1.0. BK=128; LDS row = 128 B = 8 x 16B positions.
// Swizzle (rule #21, both sides): LDS(row,pos) holds global 16B chunk
// gpos = pos ^ (row&7). Stage pre-swizzles the GLOBAL source address (LDS
// written linearly by global_load_lds); reads XOR the position back.
// Bank audit: every ds_read_b128 lands uniformly 8 dwords/bank (conflict-free).
// ---------------------------------------------------------------------------
__global__ __launch_bounds__(256) void gemm_mxfp8_kernel(
    const uint8_t* __restrict__ Aq,   // [M][K] fp8 row-major
    const uint8_t* __restrict__ Wq,   // [N][K] fp8 row-major
    const float* __restrict__ wscale,
    const float* __restrict__ iscale,
    float* __restrict__ out)
{
    __shared__ uint8_t smA[2][BM * BK];  // 16 KB each
    __shared__ uint8_t smB[2][BN * BK];  // 16 KB each (total 64 KB)

    const int tid  = threadIdx.x;
    const int lane = tid & 63;
    const int wid  = tid >> 6;

    // Bijective XCD swizzle (2048 % 8 == 0); 16 consecutive wg share bm.
    const int bid = blockIdx.x;
    const int wg  = (bid & 7) * (GRID_M * GRID_N / 8) + (bid >> 3);
    const int bm  = wg >> 4;
    const int bn  = wg & 15;
    const int rowBase = bm * BM;
    const int colBase = bn * BN;

    // Wave's 64x64 output quadrant
    const int wrow = (wid >> 1) * 64;
    const int wcol = (wid & 1) * 64;

    // Staging: per issue a wave covers 8 rows x 128 B. Lane l -> LDS row
    // chunk*8 + (l>>3), pos16 (l&7). Global source position pre-swizzled.
    const int srow = lane >> 3;                       // 0..7
    const int spos = ((lane & 7) ^ srow) * 16;        // gpos = pos ^ (row&7)
    auto stage = [&](int buf, int kt) {
        const int k0 = kt * BK;
#pragma unroll
        for (int j = 0; j < 4; ++j) {
            const int chunk = j * 4 + wid;            // 0..15
            const int row   = chunk * 8 + srow;
            const uint8_t* gA = Aq + (size_t)(rowBase + row) * K_DIM + k0 + spos;
            __builtin_amdgcn_global_load_lds(
                (const __attribute__((address_space(1))) void*)gA,
                (__attribute__((address_space(3))) void*)&smA[buf][chunk * 1024],
                16, 0, 0);
            const uint8_t* gB = Wq + (size_t)(colBase + row) * K_DIM + k0 + spos;
            __builtin_amdgcn_global_load_lds(
                (const __attribute__((address_space(1))) void*)gB,
                (__attribute__((address_space(3))) void*)&smB[buf][chunk * 1024],
                16, 0, 0);
        }
    };

    // Fragment read geometry: lane holds row (lane&15), k-block (lane>>4)
    // (32 contiguous bytes = one MX block). p0 = LDS pos of block's low 16B.
    const int afr   = lane & 15;
    const int rx    = lane & 7;                 // row&7 (wrow, m*16 are mult of 8)
    const int kblk2 = (lane >> 4) * 2;          // 16B-pos of block start (even)
    const int p0    = kblk2 ^ rx;               // low half pos; high half = p0^1

    f32x4 acc[4][4] = {};

    stage(0, 0);
    __syncthreads();

    for (int kt = 0; kt < NTILES; ++kt) {
        const int cur = kt & 1;
        if (kt + 1 < NTILES) stage(cur ^ 1, kt + 1);   // DMA prefetch under compute

        const uint8_t* pA = smA[cur];
        const uint8_t* pB = smB[cur];
        i32x8 av[4], bv[4];
#pragma unroll
        for (int m = 0; m < 4; ++m) {
            const int ro = (wrow + m * 16 + afr) * BK;
            u32x4 lo = *(const u32x4*)(pA + ro + p0 * 16);
            u32x4 hi = *(const u32x4*)(pA + ro + (p0 ^ 1) * 16);
            av[m] = (i32x8){(int)lo.x, (int)lo.y, (int)lo.z, (int)lo.w,
                            (int)hi.x, (int)hi.y, (int)hi.z, (int)hi.w};
        }
#pragma unroll
        for (int n = 0; n < 4; ++n) {
            const int ro = (wcol + n * 16 + afr) * BK;
            u32x4 lo = *(const u32x4*)(pB + ro + p0 * 16);
            u32x4 hi = *(const u32x4*)(pB + ro + (p0 ^ 1) * 16);
            bv[n] = (i32x8){(int)lo.x, (int)lo.y, (int)lo.z, (int)lo.w,
                            (int)hi.x, (int)hi.y, (int)hi.z, (int)hi.w};
        }
#pragma unroll
        for (int m = 0; m < 4; ++m)
#pragma unroll
            for (int n = 0; n < 4; ++n)
                acc[m][n] = __builtin_amdgcn_mfma_scale_f32_16x16x128_f8f6f4(
                    av[m], bv[n], acc[m][n],
                    0 /*A fmt: fp8 e4m3*/, 0 /*B fmt: fp8 e4m3*/,
                    0, SCALE_ONE, 0, SCALE_ONE);
        __syncthreads();
    }

    // C/D layout (16x16 shapes, dtype/shape-determined; validated rounds 4-6):
    // col = lane&15, row = (lane>>4)*4 + reg.
    const float sc = wscale[0] * iscale[0];
    const int crow = (lane >> 4) << 2;
    const int ccol = lane & 15;
#pragma unroll
    for (int m = 0; m < 4; ++m) {
#pragma unroll
        for (int n = 0; n < 4; ++n) {
            const size_t base = (size_t)(rowBase + wrow + m * 16 + crow) * N_DIM
                              + (colBase + wcol + n * 16 + ccol);
#pragma unroll
            for (int r = 0; r < 4; ++r)
                out[base + (size_t)r * N_DIM] = acc[m][n][r] * sc;
        }
    }
}

// ---------------------------------------------------------------------------
// Fallback (ws too small): proven round-4 fused kernel, unchanged.
// ---------------------------------------------------------------------------
__global__ __launch_bounds__(256) void fused_fp8_gemm(
    const float* __restrict__ X, const float* __restrict__ Wf,
    const float* __restrict__ wscale, const float* __restrict__ iscale,
    float* __restrict__ out)
{
    __shared__ uint8_t smA[2][128 * 64];
    __shared__ uint8_t smB[2][128 * 64];

    const int tid  = threadIdx.x;
    const int lane = tid & 63;
    const int wid  = tid >> 6;

    const float s  = iscale[0];
    const float rs = 1.0f / s;
    const float sc = wscale[0] * s;

    const int bid = blockIdx.x;
    const int wg  = (bid & 7) * (GRID_M * GRID_N / 8) + (bid >> 3);
    const int bm  = wg >> 4;
    const int bn  = wg & 15;
    const int rowBase = bm * BM;
    const int colBase = bn * BN;
    const int wrow = (wid >> 1) * 64;
    const int wcol = (wid & 1) * 64;
    const int ar = tid >> 1;
    const int ah = (tid & 1) * 32;

    const float* Xrow = X  + (size_t)(rowBase + ar) * K_DIM;
    const float* Wrow = Wf + (size_t)(colBase + ar) * K_DIM;

    float4 areg[8], breg[8];
    auto load_tile = [&](int kt) {
        const int k0 = kt * 64;
#pragma unroll
        for (int j = 0; j < 8; ++j) areg[j] = *(const float4*)(Xrow + k0 + ah + j * 4);
#pragma unroll
        for (int j = 0; j < 8; ++j) breg[j] = *(const float4*)(Wrow + k0 + ah + j * 4);
    };
    auto write_tile = [&](int buf) {
        uint32_t aq[8], bq[8];
#pragma unroll
        for (int j = 0; j < 8; ++j) { aq[j] = quant4(areg[j], rs); bq[j] = quant4(breg[j], 1.0f); }
        *(u32x4*)&smA[buf][ar * 64 + ah]      = *(const u32x4*)&aq[0];
        *(u32x4*)&smA[buf][ar * 64 + ah + 16] = *(const u32x4*)&aq[4];
        *(u32x4*)&smB[buf][ar * 64 + ah]      = *(const u32x4*)&bq[0];
        *(u32x4*)&smB[buf][ar * 64 + ah + 16] = *(const u32x4*)&bq[4];
    };

    f32x4 acc[4][4] = {};
    load_tile(0); write_tile(0); __syncthreads();
    for (int kt = 0; kt < 32; ++kt) {
        const int cur = kt & 1;
        if (kt + 1 < 32) load_tile(kt + 1);
        const uint8_t* pA = smA[cur];
        const uint8_t* pB = smB[cur];
        const int afr = lane & 15, koff = (lane >> 4) << 3;
#pragma unroll
        for (int kk = 0; kk < 2; ++kk) {
            long long a[4], b[4];
#pragma unroll
            for (int m = 0; m < 4; ++m)
                a[m] = *(const long long*)(pA + (wrow + m * 16 + afr) * 64 + kk * 32 + koff);
#pragma unroll
            for (int n = 0; n < 4; ++n)
                b[n] = *(const long long*)(pB + (wcol + n * 16 + afr) * 64 + kk * 32 + koff);
#pragma unroll
            for (int m = 0; m < 4; ++m)
#pragma unroll
                for (int n = 0; n < 4; ++n)
                    acc[m][n] = __builtin_amdgcn_mfma_f32_16x16x32_fp8_fp8(
                        a[m], b[n], acc[m][n], 0, 0, 0);
        }
        if (kt + 1 < 32) write_tile(cur ^ 1);
        __syncthreads();
    }
    const int crow = (lane >> 4) << 2, ccol = lane & 15;
#pragma unroll
    for (int m = 0; m < 4; ++m)
#pragma unroll
        for (int n = 0; n < 4; ++n) {
            const size_t base = (size_t)(rowBase + wrow + m * 16 + crow) * N_DIM
                              + (colBase + wcol + n * 16 + ccol);
#pragma unroll
            for (int r = 0; r < 4; ++r)
                out[base + (size_t)r * N_DIM] = acc[m][n][r] * sc;
        }
}

extern "C" void kernel_launch(void* const* d_in, const int* in_sizes, int n_in,
                              void* d_out, int out_size, void* d_ws, size_t ws_size,
                              hipStream_t stream) {
    const float* x      = (const float*)d_in[0];
    const float* w      = (const float*)d_in[1];   // fp8 values stored as f32
    const float* wscale = (const float*)d_in[2];
    const float* iscale = (const float*)d_in[3];
    float*       out    = (float*)d_out;

    const size_t needA = (size_t)M_DIM * K_DIM;    // 33.5 MB fp8 X
    const size_t needW = (size_t)N_DIM * K_DIM;    //  4.2 MB fp8 W
    if (ws_size >= needA + needW) {
        uint32_t* xq = (uint32_t*)d_ws;
        uint32_t* wq = (uint32_t*)((uint8_t*)d_ws + needA);
        quant_x_kernel<<<2048, 256, 0, stream>>>(x, iscale, xq);
        conv_w_kernel<<<1024, 256, 0, stream>>>(w, wq);
        gemm_mxfp8_kernel<<<GRID_M * GRID_N, 256, 0, stream>>>(
            (const uint8_t*)xq, (const uint8_t*)wq, wscale, iscale, out);
    } else {
        fused_fp8_gemm<<<GRID_M * GRID_N, 256, 0, stream>>>(x, w, wscale, iscale, out);
    }
}